// Round 7
// baseline (7961.066 us; speedup 1.0000x reference)
//
#include <hip/hip_runtime.h>

#define NU 200000
#define NR 50000
#define DD 64
#define NE 2000000
#define NQ 500000
#define SCAN_ITEMS 1024

// -------------------- degree count (int) --------------------
__global__ void count_int_kernel(const int* __restrict__ dst, int* __restrict__ cnt, int n) {
    int i = blockIdx.x * blockDim.x + threadIdx.x;
    if (i < n) atomicAdd(&cnt[dst[i]], 1);
}

// -------------------- scan: per-block reduce --------------------
__global__ void scan_reduce_kernel(const int* __restrict__ cnt, int* __restrict__ bsum, int n) {
    __shared__ int s[256];
    int base = blockIdx.x * SCAN_ITEMS;
    int t = 0;
    for (int i = threadIdx.x; i < SCAN_ITEMS; i += 256) {
        int g = base + i;
        t += (g < n) ? cnt[g] : 0;
    }
    s[threadIdx.x] = t;
    __syncthreads();
    for (int off = 128; off > 0; off >>= 1) {
        if (threadIdx.x < off) s[threadIdx.x] += s[threadIdx.x + off];
        __syncthreads();
    }
    if (threadIdx.x == 0) bsum[blockIdx.x] = s[0];
}

// -------------------- scan: single-block exclusive scan of block sums ------
__global__ void scan_bsum_kernel(int* __restrict__ bsum, int nb) {
    __shared__ int a[256], b[256];
    int tid = threadIdx.x;
    a[tid] = (tid < nb) ? bsum[tid] : 0;
    __syncthreads();
    int* cur = a; int* alt = b;
    for (int off = 1; off < 256; off <<= 1) {
        int t = cur[tid];
        if (tid >= off) t += cur[tid - off];
        alt[tid] = t;
        __syncthreads();
        int* tmp = cur; cur = alt; alt = tmp;
    }
    int excl = (tid == 0) ? 0 : cur[tid - 1];
    if (tid < nb) bsum[tid] = excl;
}

// -------------------- scan: write exclusive row starts --------------------
__global__ void scan_write_kernel(const int* __restrict__ cnt, const int* __restrict__ bsum,
                                  int* __restrict__ rs, int n, int total) {
    __shared__ int sa[256], sb[256];
    int tid = threadIdx.x;
    int base = blockIdx.x * SCAN_ITEMS;
    int loc[4];
    int t = 0;
#pragma unroll
    for (int i = 0; i < 4; i++) {
        int g = base + tid * 4 + i;
        int v = (g < n) ? cnt[g] : 0;
        loc[i] = t;
        t += v;
    }
    sa[tid] = t;
    __syncthreads();
    int* cur = sa; int* alt = sb;
    for (int off = 1; off < 256; off <<= 1) {
        int x = cur[tid];
        if (tid >= off) x += cur[tid - off];
        alt[tid] = x;
        __syncthreads();
        int* tmp = cur; cur = alt; alt = tmp;
    }
    int texcl = cur[tid] - t;  // exclusive prefix of this thread
    int off0 = bsum[blockIdx.x] + texcl;
#pragma unroll
    for (int i = 0; i < 4; i++) {
        int g = base + tid * 4 + i;
        if (g < n) rs[g] = off0 + loc[i];
    }
    if (blockIdx.x == 0 && tid == 0) rs[n] = total;
}

// -------------------- CSR fill --------------------
__global__ void fill_csr_kernel(const int* __restrict__ src, const int* __restrict__ dst,
                                const int* __restrict__ rs, int* __restrict__ cursor,
                                int* __restrict__ csr, int n) {
    int e = blockIdx.x * blockDim.x + threadIdx.x;
    if (e < n) {
        int d = dst[e];
        int pos = atomicAdd(&cursor[d], 1);
        csr[rs[d] + pos] = src[e];
    }
}

// -------------------- gather mean: wave per dst row --------------------
__global__ __launch_bounds__(256)
void gather_mean_kernel(const float* __restrict__ h, const int* __restrict__ csr,
                        const int* __restrict__ rs, float* __restrict__ mean, int nrows) {
    int lane = threadIdx.x & 63;
    int wave = blockIdx.x * 4 + (threadIdx.x >> 6);
    if (wave >= nrows) return;
    int r = wave;
    int s = rs[r], e = rs[r + 1];
    float a0 = 0.f, a1 = 0.f, a2 = 0.f, a3 = 0.f;
    for (int j = s; j < e; j += 64) {
        int rem = e - j;
        int nch = rem < 64 ? rem : 64;
        int li = lane < nch ? lane : nch - 1;
        int idx = csr[j + li];  // clamped: all lanes hold a valid id
        for (int kk = 0; kk < nch; kk += 4) {
            int i0 = __shfl(idx, kk);
            int i1 = __shfl(idx, kk + 1);
            int i2 = __shfl(idx, kk + 2);
            int i3 = __shfl(idx, kk + 3);
            float v0 = h[i0 * DD + lane];
            float v1 = h[i1 * DD + lane];
            float v2 = h[i2 * DD + lane];
            float v3 = h[i3 * DD + lane];
            a0 += v0;                              // kk < nch always
            a1 += (kk + 1 < nch) ? v1 : 0.f;
            a2 += (kk + 2 < nch) ? v2 : 0.f;
            a3 += (kk + 3 < nch) ? v3 : 0.f;
        }
    }
    float acc = (a0 + a1) + (a2 + a3);
    float inv = 1.0f / fmaxf((float)(e - s), 1.0f);
    mean[r * DD + lane] = acc * inv;
}

#define DOT4(A, B) ((A).x*(B).x + (A).y*(B).y + (A).z*(B).z + (A).w*(B).w)

// -------------------- SAGE linear: column-parallel, wave per row ----------
// lane l owns output column l; holds Wl[l][:], Wr[l][:] in VGPRs (loaded once).
// Per row: wave-broadcast VMEM loads of the row, 128 FMAs, 1 coalesced store.
__global__ __launch_bounds__(256, 2)
void sage_linear_kernel(const float* __restrict__ mean, const float* __restrict__ h,
                        const float* __restrict__ Wl, const float* __restrict__ Wr,
                        const float* __restrict__ bias,
                        float* __restrict__ out, int n, int do_relu) {
    int lane = threadIdx.x & 63;
    int wid = (blockIdx.x * 256 + threadIdx.x) >> 6;   // global wave id (wave-uniform)
    int nw = (gridDim.x * 256) >> 6;
    float wl[DD], wr[DD];
    const float* wlp = Wl + lane * DD;
    const float* wrp = Wr + lane * DD;
#pragma unroll
    for (int i = 0; i < 16; i++) {
        float4 a = *(const float4*)(wlp + 4 * i);
        float4 b = *(const float4*)(wrp + 4 * i);
        wl[4*i] = a.x; wl[4*i+1] = a.y; wl[4*i+2] = a.z; wl[4*i+3] = a.w;
        wr[4*i] = b.x; wr[4*i+1] = b.y; wr[4*i+2] = b.z; wr[4*i+3] = b.w;
    }
    float b0 = bias[lane];
    for (int r = wid; r < n; r += nw) {
        const float* mrow = mean + (size_t)r * DD;
        const float* xrow = h + (size_t)r * DD;
        float acc = b0;
#pragma unroll
        for (int kc = 0; kc < DD; kc += 16) {
            float4 m0 = *(const float4*)(mrow + kc);
            float4 m1 = *(const float4*)(mrow + kc + 4);
            float4 m2 = *(const float4*)(mrow + kc + 8);
            float4 m3 = *(const float4*)(mrow + kc + 12);
            float4 x0 = *(const float4*)(xrow + kc);
            float4 x1 = *(const float4*)(xrow + kc + 4);
            float4 x2 = *(const float4*)(xrow + kc + 8);
            float4 x3 = *(const float4*)(xrow + kc + 12);
            acc += m0.x*wl[kc]    + m0.y*wl[kc+1]  + m0.z*wl[kc+2]  + m0.w*wl[kc+3]
                 + m1.x*wl[kc+4]  + m1.y*wl[kc+5]  + m1.z*wl[kc+6]  + m1.w*wl[kc+7]
                 + m2.x*wl[kc+8]  + m2.y*wl[kc+9]  + m2.z*wl[kc+10] + m2.w*wl[kc+11]
                 + m3.x*wl[kc+12] + m3.y*wl[kc+13] + m3.z*wl[kc+14] + m3.w*wl[kc+15]
                 + x0.x*wr[kc]    + x0.y*wr[kc+1]  + x0.z*wr[kc+2]  + x0.w*wr[kc+3]
                 + x1.x*wr[kc+4]  + x1.y*wr[kc+5]  + x1.z*wr[kc+6]  + x1.w*wr[kc+7]
                 + x2.x*wr[kc+8]  + x2.y*wr[kc+9]  + x2.z*wr[kc+10] + x2.w*wr[kc+11]
                 + x3.x*wr[kc+12] + x3.y*wr[kc+13] + x3.z*wr[kc+14] + x3.w*wr[kc+15];
        }
        if (do_relu) acc = fmaxf(acc, 0.f);
        out[(size_t)r * DD + lane] = acc;
    }
}

// -------------------- decoder layer-1 precompute (column-parallel) --------
// P[r][c] = (add_bias ? db1[c] : 0) + sum_k h[r][k] * dW1[c*128 + koff + k]
__global__ __launch_bounds__(256, 2)
void precompute_kernel(const float* __restrict__ h, const float* __restrict__ dW1,
                       const float* __restrict__ db1, float* __restrict__ P,
                       int n, int koff, int add_bias) {
    int lane = threadIdx.x & 63;
    int wid = (blockIdx.x * 256 + threadIdx.x) >> 6;
    int nw = (gridDim.x * 256) >> 6;
    float wv[DD];
    const float* wp = dW1 + lane * 2 * DD + koff;
#pragma unroll
    for (int i = 0; i < 16; i++) {
        float4 a = *(const float4*)(wp + 4 * i);
        wv[4*i] = a.x; wv[4*i+1] = a.y; wv[4*i+2] = a.z; wv[4*i+3] = a.w;
    }
    float b0 = add_bias ? db1[lane] : 0.f;
    for (int r = wid; r < n; r += nw) {
        const float* xrow = h + (size_t)r * DD;
        float acc = b0;
#pragma unroll
        for (int kc = 0; kc < DD; kc += 16) {
            float4 x0 = *(const float4*)(xrow + kc);
            float4 x1 = *(const float4*)(xrow + kc + 4);
            float4 x2 = *(const float4*)(xrow + kc + 8);
            float4 x3 = *(const float4*)(xrow + kc + 12);
            acc += x0.x*wv[kc]    + x0.y*wv[kc+1]  + x0.z*wv[kc+2]  + x0.w*wv[kc+3]
                 + x1.x*wv[kc+4]  + x1.y*wv[kc+5]  + x1.z*wv[kc+6]  + x1.w*wv[kc+7]
                 + x2.x*wv[kc+8]  + x2.y*wv[kc+9]  + x2.z*wv[kc+10] + x2.w*wv[kc+11]
                 + x3.x*wv[kc+12] + x3.y*wv[kc+13] + x3.z*wv[kc+14] + x3.w*wv[kc+15];
        }
        P[(size_t)r * DD + lane] = acc;
    }
}

// -------------------- fused decoder: thread per query ----------------------
// z1 = relu(Pu[row]+Pr[col]) in 16 named float4s; weight stream forced to
// VMEM broadcast loads via opaque divergent zero (defeats s_load serialization).
#define ZCOMB(Zi, i) float4 Zi; { float4 u_ = pu[i]; float4 v_ = pr[i]; \
    Zi.x = fmaxf(u_.x + v_.x, 0.f); Zi.y = fmaxf(u_.y + v_.y, 0.f); \
    Zi.z = fmaxf(u_.z + v_.z, 0.f); Zi.w = fmaxf(u_.w + v_.w, 0.f); }

__global__ __launch_bounds__(256, 2)
void decoder_kernel(const float* __restrict__ Pu, const float* __restrict__ Pr,
                    const int* __restrict__ el_row, const int* __restrict__ el_col,
                    const float* __restrict__ dW2, const float* __restrict__ db2,
                    const float* __restrict__ dW3, const float* __restrict__ db3,
                    float* __restrict__ out) {
    int q = blockIdx.x * 256 + threadIdx.x;
    if (q >= NQ) return;
    int dz = __builtin_amdgcn_mbcnt_lo(0u, 0u);   // divergent 0
    const float* w2 = dW2 + dz;
    const float* b2 = db2 + dz;
    const float* w3 = dW3 + dz;
    int row = el_row[q], col = el_col[q];
    const float4* pu = (const float4*)(Pu + (size_t)row * DD);
    const float4* pr = (const float4*)(Pr + (size_t)col * DD);
    ZCOMB(z0, 0)  ZCOMB(z1, 1)  ZCOMB(z2, 2)  ZCOMB(z3, 3)
    ZCOMB(z4, 4)  ZCOMB(z5, 5)  ZCOMB(z6, 6)  ZCOMB(z7, 7)
    ZCOMB(z8, 8)  ZCOMB(z9, 9)  ZCOMB(z10, 10) ZCOMB(z11, 11)
    ZCOMB(z12, 12) ZCOMB(z13, 13) ZCOMB(z14, 14) ZCOMB(z15, 15)
    float o = db3[0];
#pragma unroll 4
    for (int c = 0; c < DD; c++) {
        const float4* wp = (const float4*)(w2 + c * DD);
        float s = b2[c]
            + DOT4(z0, wp[0])  + DOT4(z1, wp[1])  + DOT4(z2, wp[2])  + DOT4(z3, wp[3])
            + DOT4(z4, wp[4])  + DOT4(z5, wp[5])  + DOT4(z6, wp[6])  + DOT4(z7, wp[7])
            + DOT4(z8, wp[8])  + DOT4(z9, wp[9])  + DOT4(z10, wp[10]) + DOT4(z11, wp[11])
            + DOT4(z12, wp[12]) + DOT4(z13, wp[13]) + DOT4(z14, wp[14]) + DOT4(z15, wp[15]);
        o += fmaxf(s, 0.f) * w3[c];
    }
    out[q] = o;
}

extern "C" void kernel_launch(void* const* d_in, const int* in_sizes, int n_in,
                              void* d_out, int out_size, void* d_ws, size_t ws_size,
                              hipStream_t stream) {
    const float* x_user = (const float*)d_in[0];
    const float* x_rest = (const float*)d_in[1];
    const float* Wl     = (const float*)d_in[2];   // [3,2,64,64]
    const float* Wr     = (const float*)d_in[3];
    const float* bl     = (const float*)d_in[4];   // [3,2,64]
    const float* dW1    = (const float*)d_in[5];   // [64,128]
    const float* db1    = (const float*)d_in[6];
    const float* dW2    = (const float*)d_in[7];   // [64,64]
    const float* db2    = (const float*)d_in[8];
    const float* dW3    = (const float*)d_in[9];   // [1,64]
    const float* db3    = (const float*)d_in[10];
    const int* ur_src   = (const int*)d_in[11];
    const int* ur_dst   = (const int*)d_in[12];
    const int* ru_src   = (const int*)d_in[13];
    const int* ru_dst   = (const int*)d_in[14];
    const int* el_row   = (const int*)d_in[15];
    const int* el_col   = (const int*)d_in[16];
    float* out = (float*)d_out;

    char* w = (char*)d_ws;
    size_t off = 0;
    auto alloc = [&](size_t bytes) -> void* {
        void* p = (void*)(w + off);
        off += (bytes + 255) & ~(size_t)255;
        return p;
    };
    float* hu0  = (float*)alloc((size_t)NU * DD * 4);
    float* hu1  = (float*)alloc((size_t)NU * DD * 4);   // also reused for P_u
    float* hr0  = (float*)alloc((size_t)NR * DD * 4);
    float* hr1  = (float*)alloc((size_t)NR * DD * 4);   // also reused for P_r
    float* mean = (float*)alloc((size_t)NU * DD * 4);   // shared by both sides
    int* csr_u  = (int*)alloc((size_t)NE * 4);
    int* csr_r  = (int*)alloc((size_t)NE * 4);
    int* rs_u   = (int*)alloc((size_t)(NU + 1) * 4);
    int* rs_r   = (int*)alloc((size_t)(NR + 1) * 4);
    int* cnt_u  = (int*)alloc((size_t)NU * 4);          // histogram, then cursor
    int* cnt_r  = (int*)alloc((size_t)NR * 4);
    int* bsum_u = (int*)alloc(256 * 4);
    int* bsum_r = (int*)alloc(256 * 4);

    const int nb_u = (NU + SCAN_ITEMS - 1) / SCAN_ITEMS;  // 196
    const int nb_r = (NR + SCAN_ITEMS - 1) / SCAN_ITEMS;  // 49
    const int egrid = (NE + 255) / 256;

    // ---- build CSR for both edge lists (once per call) ----
    hipMemsetAsync(cnt_u, 0, (size_t)NU * 4, stream);
    hipMemsetAsync(cnt_r, 0, (size_t)NR * 4, stream);
    count_int_kernel<<<egrid, 256, 0, stream>>>(ru_dst, cnt_u, NE);
    count_int_kernel<<<egrid, 256, 0, stream>>>(ur_dst, cnt_r, NE);
    scan_reduce_kernel<<<nb_u, 256, 0, stream>>>(cnt_u, bsum_u, NU);
    scan_bsum_kernel<<<1, 256, 0, stream>>>(bsum_u, nb_u);
    scan_write_kernel<<<nb_u, 256, 0, stream>>>(cnt_u, bsum_u, rs_u, NU, NE);
    scan_reduce_kernel<<<nb_r, 256, 0, stream>>>(cnt_r, bsum_r, NR);
    scan_bsum_kernel<<<1, 256, 0, stream>>>(bsum_r, nb_r);
    scan_write_kernel<<<nb_r, 256, 0, stream>>>(cnt_r, bsum_r, rs_r, NR, NE);
    hipMemsetAsync(cnt_u, 0, (size_t)NU * 4, stream);
    hipMemsetAsync(cnt_r, 0, (size_t)NR * 4, stream);
    fill_csr_kernel<<<egrid, 256, 0, stream>>>(ru_src, ru_dst, rs_u, cnt_u, csr_u, NE);
    fill_csr_kernel<<<egrid, 256, 0, stream>>>(ur_src, ur_dst, rs_r, cnt_r, csr_r, NE);

    // ---- 3 SAGE layers ----
    const float* cu = x_user;
    const float* cr = x_rest;
    float* nu_[3] = {hu0, hu1, hu0};
    float* nr_[3] = {hr0, hr1, hr0};

    for (int l = 0; l < 3; l++) {
        const float* Wl_r = Wl + (size_t)(l * 2 + 0) * DD * DD;
        const float* Wr_r = Wr + (size_t)(l * 2 + 0) * DD * DD;
        const float* bl_r = bl + (size_t)(l * 2 + 0) * DD;
        const float* Wl_u = Wl + (size_t)(l * 2 + 1) * DD * DD;
        const float* Wr_u = Wr + (size_t)(l * 2 + 1) * DD * DD;
        const float* bl_u = bl + (size_t)(l * 2 + 1) * DD;
        int relu = (l < 2) ? 1 : 0;

        // restaurant side: mean over user rows (ur edges), then linear
        gather_mean_kernel<<<(NR + 3) / 4, 256, 0, stream>>>(cu, csr_r, rs_r, mean, NR);
        sage_linear_kernel<<<768, 256, 0, stream>>>(mean, cr, Wl_r, Wr_r, bl_r, nr_[l], NR, relu);
        // user side: mean over restaurant rows (ru edges), then linear
        gather_mean_kernel<<<(NU + 3) / 4, 256, 0, stream>>>(cr, csr_u, rs_u, mean, NU);
        sage_linear_kernel<<<768, 256, 0, stream>>>(mean, cu, Wl_u, Wr_u, bl_u, nu_[l], NU, relu);

        cu = nu_[l];
        cr = nr_[l];
    }
    // final: cu == hu0, cr == hr0; hu1/hr1 are free -> hold P_u/P_r
    float* P_u = hu1;
    float* P_r = hr1;
    precompute_kernel<<<768, 256, 0, stream>>>(cu, dW1, db1, P_u, NU, 0, 1);
    precompute_kernel<<<768, 256, 0, stream>>>(cr, dW1, db1, P_r, NR, DD, 0);

    decoder_kernel<<<(NQ + 255) / 256, 256, 0, stream>>>(P_u, P_r, el_row, el_col,
                                                         dW2, db2, dW3, db3, out);
}

// Round 8
// 1618.397 us; speedup vs baseline: 4.9191x; 4.9191x over previous
//
#include <hip/hip_runtime.h>

#define NU 200000
#define NR 50000
#define DD 64
#define NE 2000000
#define NQ 500000
#define SCAN_ITEMS 1024

// -------------------- degree count (int) --------------------
__global__ void count_int_kernel(const int* __restrict__ dst, int* __restrict__ cnt, int n) {
    int i = blockIdx.x * blockDim.x + threadIdx.x;
    if (i < n) atomicAdd(&cnt[dst[i]], 1);
}

// -------------------- scan: per-block reduce --------------------
__global__ void scan_reduce_kernel(const int* __restrict__ cnt, int* __restrict__ bsum, int n) {
    __shared__ int s[256];
    int base = blockIdx.x * SCAN_ITEMS;
    int t = 0;
    for (int i = threadIdx.x; i < SCAN_ITEMS; i += 256) {
        int g = base + i;
        t += (g < n) ? cnt[g] : 0;
    }
    s[threadIdx.x] = t;
    __syncthreads();
    for (int off = 128; off > 0; off >>= 1) {
        if (threadIdx.x < off) s[threadIdx.x] += s[threadIdx.x + off];
        __syncthreads();
    }
    if (threadIdx.x == 0) bsum[blockIdx.x] = s[0];
}

// -------------------- scan: single-block exclusive scan of block sums ------
__global__ void scan_bsum_kernel(int* __restrict__ bsum, int nb) {
    __shared__ int a[256], b[256];
    int tid = threadIdx.x;
    a[tid] = (tid < nb) ? bsum[tid] : 0;
    __syncthreads();
    int* cur = a; int* alt = b;
    for (int off = 1; off < 256; off <<= 1) {
        int t = cur[tid];
        if (tid >= off) t += cur[tid - off];
        alt[tid] = t;
        __syncthreads();
        int* tmp = cur; cur = alt; alt = tmp;
    }
    int excl = (tid == 0) ? 0 : cur[tid - 1];
    if (tid < nb) bsum[tid] = excl;
}

// -------------------- scan: write exclusive row starts --------------------
__global__ void scan_write_kernel(const int* __restrict__ cnt, const int* __restrict__ bsum,
                                  int* __restrict__ rs, int n, int total) {
    __shared__ int sa[256], sb[256];
    int tid = threadIdx.x;
    int base = blockIdx.x * SCAN_ITEMS;
    int loc[4];
    int t = 0;
#pragma unroll
    for (int i = 0; i < 4; i++) {
        int g = base + tid * 4 + i;
        int v = (g < n) ? cnt[g] : 0;
        loc[i] = t;
        t += v;
    }
    sa[tid] = t;
    __syncthreads();
    int* cur = sa; int* alt = sb;
    for (int off = 1; off < 256; off <<= 1) {
        int x = cur[tid];
        if (tid >= off) x += cur[tid - off];
        alt[tid] = x;
        __syncthreads();
        int* tmp = cur; cur = alt; alt = tmp;
    }
    int texcl = cur[tid] - t;  // exclusive prefix of this thread
    int off0 = bsum[blockIdx.x] + texcl;
#pragma unroll
    for (int i = 0; i < 4; i++) {
        int g = base + tid * 4 + i;
        if (g < n) rs[g] = off0 + loc[i];
    }
    if (blockIdx.x == 0 && tid == 0) rs[n] = total;
}

// -------------------- CSR fill --------------------
__global__ void fill_csr_kernel(const int* __restrict__ src, const int* __restrict__ dst,
                                const int* __restrict__ rs, int* __restrict__ cursor,
                                int* __restrict__ csr, int n) {
    int e = blockIdx.x * blockDim.x + threadIdx.x;
    if (e < n) {
        int d = dst[e];
        int pos = atomicAdd(&cursor[d], 1);
        csr[rs[d] + pos] = src[e];
    }
}

// -------------------- gather mean: wave per dst row --------------------
__global__ __launch_bounds__(256)
void gather_mean_kernel(const float* __restrict__ h, const int* __restrict__ csr,
                        const int* __restrict__ rs, float* __restrict__ mean, int nrows) {
    int lane = threadIdx.x & 63;
    int wave = blockIdx.x * 4 + (threadIdx.x >> 6);
    if (wave >= nrows) return;
    int r = wave;
    int s = rs[r], e = rs[r + 1];
    float a0 = 0.f, a1 = 0.f, a2 = 0.f, a3 = 0.f;
    for (int j = s; j < e; j += 64) {
        int rem = e - j;
        int nch = rem < 64 ? rem : 64;
        int li = lane < nch ? lane : nch - 1;
        int idx = csr[j + li];  // clamped: all lanes hold a valid id
        for (int kk = 0; kk < nch; kk += 4) {
            int i0 = __shfl(idx, kk);
            int i1 = __shfl(idx, kk + 1);
            int i2 = __shfl(idx, kk + 2);
            int i3 = __shfl(idx, kk + 3);
            float v0 = h[i0 * DD + lane];
            float v1 = h[i1 * DD + lane];
            float v2 = h[i2 * DD + lane];
            float v3 = h[i3 * DD + lane];
            a0 += v0;                              // kk < nch always
            a1 += (kk + 1 < nch) ? v1 : 0.f;
            a2 += (kk + 2 < nch) ? v2 : 0.f;
            a3 += (kk + 3 < nch) ? v3 : 0.f;
        }
    }
    float acc = (a0 + a1) + (a2 + a3);
    float inv = 1.0f / fmaxf((float)(e - s), 1.0f);
    mean[r * DD + lane] = acc * inv;
}

// ==== macro toolkit: named float4 accumulators + LDS broadcast weights ====
// All lanes of a wave read the SAME LDS address (weights are row-invariant)
// -> conflict-free broadcast ds_read_b128, no s_load serialization, no alloca.
#define DOT4(A, B) ((A).x*(B).x + (A).y*(B).y + (A).z*(B).z + (A).w*(B).w)

#define SAGE_COL(A, c) { \
    const float4* wl_ = (const float4*)(Wls + (c) * DD + kc); \
    const float4* wr_ = (const float4*)(Wrs + (c) * DD + kc); \
    float4 l0_ = wl_[0], l1_ = wl_[1], q0_ = wr_[0], q1_ = wr_[1]; \
    A += DOT4(m0, l0_) + DOT4(m1, l1_) + DOT4(x0, q0_) + DOT4(x1, q1_); }

#define SAGE_COL4(V, base) SAGE_COL(V.x, base) SAGE_COL(V.y, (base)+1) \
                           SAGE_COL(V.z, (base)+2) SAGE_COL(V.w, (base)+3)

#define PRE_COL(A, c) { \
    const float4* wp_ = (const float4*)(Ws + (c) * DD + kc); \
    float4 w0_ = wp_[0], w1_ = wp_[1]; \
    A += DOT4(x0, w0_) + DOT4(x1, w1_); }

#define PRE_COL4(V, base) PRE_COL(V.x, base) PRE_COL(V.y, (base)+1) \
                          PRE_COL(V.z, (base)+2) PRE_COL(V.w, (base)+3)

#define RELU4(V) { V.x = fmaxf(V.x, 0.f); V.y = fmaxf(V.y, 0.f); \
                   V.z = fmaxf(V.z, 0.f); V.w = fmaxf(V.w, 0.f); }

// -------------------- SAGE linear: thread per row, LDS weights -----------
// out[r][c] = bias[c] + sum_k mean[r][k]*Wl[c][k] + sum_k h[r][k]*Wr[c][k]
__global__ __launch_bounds__(256, 2)
void sage_linear_kernel(const float* __restrict__ mean, const float* __restrict__ h,
                        const float* __restrict__ Wl, const float* __restrict__ Wr,
                        const float* __restrict__ bias,
                        float* __restrict__ out, int n, int do_relu) {
    __shared__ float Wls[DD * DD];
    __shared__ float Wrs[DD * DD];
    __shared__ float bs[DD];
    for (int i = threadIdx.x; i < DD * DD; i += 256) {
        Wls[i] = Wl[i];
        Wrs[i] = Wr[i];
    }
    if (threadIdx.x < DD) bs[threadIdx.x] = bias[threadIdx.x];
    __syncthreads();
    int r = blockIdx.x * 256 + threadIdx.x;
    if (r >= n) return;
    const float* mrow = mean + (size_t)r * DD;
    const float* xrow = h + (size_t)r * DD;
    const float4* bp = (const float4*)bs;
    float4 a0 = bp[0], a1 = bp[1], a2 = bp[2],  a3 = bp[3];
    float4 a4 = bp[4], a5 = bp[5], a6 = bp[6],  a7 = bp[7];
    float4 a8 = bp[8], a9 = bp[9], a10 = bp[10], a11 = bp[11];
    float4 a12 = bp[12], a13 = bp[13], a14 = bp[14], a15 = bp[15];
#pragma unroll 1
    for (int kc = 0; kc < DD; kc += 8) {
        float4 m0 = *(const float4*)(mrow + kc);
        float4 m1 = *(const float4*)(mrow + kc + 4);
        float4 x0 = *(const float4*)(xrow + kc);
        float4 x1 = *(const float4*)(xrow + kc + 4);
        SAGE_COL4(a0, 0)   SAGE_COL4(a1, 4)   SAGE_COL4(a2, 8)   SAGE_COL4(a3, 12)
        SAGE_COL4(a4, 16)  SAGE_COL4(a5, 20)  SAGE_COL4(a6, 24)  SAGE_COL4(a7, 28)
        SAGE_COL4(a8, 32)  SAGE_COL4(a9, 36)  SAGE_COL4(a10, 40) SAGE_COL4(a11, 44)
        SAGE_COL4(a12, 48) SAGE_COL4(a13, 52) SAGE_COL4(a14, 56) SAGE_COL4(a15, 60)
    }
    if (do_relu) {
        RELU4(a0)  RELU4(a1)  RELU4(a2)  RELU4(a3)
        RELU4(a4)  RELU4(a5)  RELU4(a6)  RELU4(a7)
        RELU4(a8)  RELU4(a9)  RELU4(a10) RELU4(a11)
        RELU4(a12) RELU4(a13) RELU4(a14) RELU4(a15)
    }
    float4* o = (float4*)(out + (size_t)r * DD);
    o[0] = a0;   o[1] = a1;   o[2] = a2;   o[3] = a3;
    o[4] = a4;   o[5] = a5;   o[6] = a6;   o[7] = a7;
    o[8] = a8;   o[9] = a9;   o[10] = a10; o[11] = a11;
    o[12] = a12; o[13] = a13; o[14] = a14; o[15] = a15;
}

// -------------------- decoder layer-1 precompute (LDS weights) -------------
// P[r][c] = (add_bias ? db1[c] : 0) + sum_k h[r][k] * dW1[c*128 + koff + k]
__global__ __launch_bounds__(256, 2)
void precompute_kernel(const float* __restrict__ h, const float* __restrict__ dW1,
                       const float* __restrict__ db1, float* __restrict__ P,
                       int n, int koff, int add_bias) {
    __shared__ float Ws[DD * DD];
    __shared__ float bs[DD];
    for (int i = threadIdx.x; i < DD * DD; i += 256) {
        int c = i >> 6, k = i & 63;
        Ws[c * DD + k] = dW1[c * 2 * DD + koff + k];
    }
    if (threadIdx.x < DD) bs[threadIdx.x] = add_bias ? db1[threadIdx.x] : 0.f;
    __syncthreads();
    int r = blockIdx.x * 256 + threadIdx.x;
    if (r >= n) return;
    const float* xrow = h + (size_t)r * DD;
    const float4* bp = (const float4*)bs;
    float4 a0 = bp[0], a1 = bp[1], a2 = bp[2],  a3 = bp[3];
    float4 a4 = bp[4], a5 = bp[5], a6 = bp[6],  a7 = bp[7];
    float4 a8 = bp[8], a9 = bp[9], a10 = bp[10], a11 = bp[11];
    float4 a12 = bp[12], a13 = bp[13], a14 = bp[14], a15 = bp[15];
#pragma unroll 1
    for (int kc = 0; kc < DD; kc += 8) {
        float4 x0 = *(const float4*)(xrow + kc);
        float4 x1 = *(const float4*)(xrow + kc + 4);
        PRE_COL4(a0, 0)   PRE_COL4(a1, 4)   PRE_COL4(a2, 8)   PRE_COL4(a3, 12)
        PRE_COL4(a4, 16)  PRE_COL4(a5, 20)  PRE_COL4(a6, 24)  PRE_COL4(a7, 28)
        PRE_COL4(a8, 32)  PRE_COL4(a9, 36)  PRE_COL4(a10, 40) PRE_COL4(a11, 44)
        PRE_COL4(a12, 48) PRE_COL4(a13, 52) PRE_COL4(a14, 56) PRE_COL4(a15, 60)
    }
    float4* o = (float4*)(P + (size_t)r * DD);
    o[0] = a0;   o[1] = a1;   o[2] = a2;   o[3] = a3;
    o[4] = a4;   o[5] = a5;   o[6] = a6;   o[7] = a7;
    o[8] = a8;   o[9] = a9;   o[10] = a10; o[11] = a11;
    o[12] = a12; o[13] = a13; o[14] = a14; o[15] = a15;
}

// -------------------- fused decoder: thread per query, LDS weights ---------
#define ZCOMB(Zi, i) float4 Zi; { float4 u_ = pu[i]; float4 v_ = pr[i]; \
    Zi.x = fmaxf(u_.x + v_.x, 0.f); Zi.y = fmaxf(u_.y + v_.y, 0.f); \
    Zi.z = fmaxf(u_.z + v_.z, 0.f); Zi.w = fmaxf(u_.w + v_.w, 0.f); }

__global__ __launch_bounds__(256, 2)
void decoder_kernel(const float* __restrict__ Pu, const float* __restrict__ Pr,
                    const int* __restrict__ el_row, const int* __restrict__ el_col,
                    const float* __restrict__ dW2, const float* __restrict__ db2,
                    const float* __restrict__ dW3, const float* __restrict__ db3,
                    float* __restrict__ out) {
    __shared__ float W2s[DD * DD];
    __shared__ float b2s[DD], w3s[DD];
    for (int i = threadIdx.x; i < DD * DD; i += 256) W2s[i] = dW2[i];
    if (threadIdx.x < DD) {
        b2s[threadIdx.x] = db2[threadIdx.x];
        w3s[threadIdx.x] = dW3[threadIdx.x];
    }
    __syncthreads();
    int q = blockIdx.x * 256 + threadIdx.x;
    if (q >= NQ) return;
    int row = el_row[q], col = el_col[q];
    const float4* pu = (const float4*)(Pu + (size_t)row * DD);
    const float4* pr = (const float4*)(Pr + (size_t)col * DD);
    ZCOMB(z0, 0)  ZCOMB(z1, 1)  ZCOMB(z2, 2)  ZCOMB(z3, 3)
    ZCOMB(z4, 4)  ZCOMB(z5, 5)  ZCOMB(z6, 6)  ZCOMB(z7, 7)
    ZCOMB(z8, 8)  ZCOMB(z9, 9)  ZCOMB(z10, 10) ZCOMB(z11, 11)
    ZCOMB(z12, 12) ZCOMB(z13, 13) ZCOMB(z14, 14) ZCOMB(z15, 15)
    float o = db3[0];
#pragma unroll 2
    for (int c = 0; c < DD; c++) {
        const float4* wp = (const float4*)(W2s + c * DD);  // broadcast, conflict-free
        float s = b2s[c]
            + DOT4(z0, wp[0])  + DOT4(z1, wp[1])  + DOT4(z2, wp[2])  + DOT4(z3, wp[3])
            + DOT4(z4, wp[4])  + DOT4(z5, wp[5])  + DOT4(z6, wp[6])  + DOT4(z7, wp[7])
            + DOT4(z8, wp[8])  + DOT4(z9, wp[9])  + DOT4(z10, wp[10]) + DOT4(z11, wp[11])
            + DOT4(z12, wp[12]) + DOT4(z13, wp[13]) + DOT4(z14, wp[14]) + DOT4(z15, wp[15]);
        o += fmaxf(s, 0.f) * w3s[c];
    }
    out[q] = o;
}

extern "C" void kernel_launch(void* const* d_in, const int* in_sizes, int n_in,
                              void* d_out, int out_size, void* d_ws, size_t ws_size,
                              hipStream_t stream) {
    const float* x_user = (const float*)d_in[0];
    const float* x_rest = (const float*)d_in[1];
    const float* Wl     = (const float*)d_in[2];   // [3,2,64,64]
    const float* Wr     = (const float*)d_in[3];
    const float* bl     = (const float*)d_in[4];   // [3,2,64]
    const float* dW1    = (const float*)d_in[5];   // [64,128]
    const float* db1    = (const float*)d_in[6];
    const float* dW2    = (const float*)d_in[7];   // [64,64]
    const float* db2    = (const float*)d_in[8];
    const float* dW3    = (const float*)d_in[9];   // [1,64]
    const float* db3    = (const float*)d_in[10];
    const int* ur_src   = (const int*)d_in[11];
    const int* ur_dst   = (const int*)d_in[12];
    const int* ru_src   = (const int*)d_in[13];
    const int* ru_dst   = (const int*)d_in[14];
    const int* el_row   = (const int*)d_in[15];
    const int* el_col   = (const int*)d_in[16];
    float* out = (float*)d_out;

    char* w = (char*)d_ws;
    size_t off = 0;
    auto alloc = [&](size_t bytes) -> void* {
        void* p = (void*)(w + off);
        off += (bytes + 255) & ~(size_t)255;
        return p;
    };
    float* hu0  = (float*)alloc((size_t)NU * DD * 4);
    float* hu1  = (float*)alloc((size_t)NU * DD * 4);   // also reused for P_u
    float* hr0  = (float*)alloc((size_t)NR * DD * 4);
    float* hr1  = (float*)alloc((size_t)NR * DD * 4);   // also reused for P_r
    float* mean = (float*)alloc((size_t)NU * DD * 4);   // shared by both sides
    int* csr_u  = (int*)alloc((size_t)NE * 4);
    int* csr_r  = (int*)alloc((size_t)NE * 4);
    int* rs_u   = (int*)alloc((size_t)(NU + 1) * 4);
    int* rs_r   = (int*)alloc((size_t)(NR + 1) * 4);
    int* cnt_u  = (int*)alloc((size_t)NU * 4);          // histogram, then cursor
    int* cnt_r  = (int*)alloc((size_t)NR * 4);
    int* bsum_u = (int*)alloc(256 * 4);
    int* bsum_r = (int*)alloc(256 * 4);

    const int nb_u = (NU + SCAN_ITEMS - 1) / SCAN_ITEMS;  // 196
    const int nb_r = (NR + SCAN_ITEMS - 1) / SCAN_ITEMS;  // 49
    const int egrid = (NE + 255) / 256;

    // ---- build CSR for both edge lists (once per call) ----
    hipMemsetAsync(cnt_u, 0, (size_t)NU * 4, stream);
    hipMemsetAsync(cnt_r, 0, (size_t)NR * 4, stream);
    count_int_kernel<<<egrid, 256, 0, stream>>>(ru_dst, cnt_u, NE);
    count_int_kernel<<<egrid, 256, 0, stream>>>(ur_dst, cnt_r, NE);
    scan_reduce_kernel<<<nb_u, 256, 0, stream>>>(cnt_u, bsum_u, NU);
    scan_bsum_kernel<<<1, 256, 0, stream>>>(bsum_u, nb_u);
    scan_write_kernel<<<nb_u, 256, 0, stream>>>(cnt_u, bsum_u, rs_u, NU, NE);
    scan_reduce_kernel<<<nb_r, 256, 0, stream>>>(cnt_r, bsum_r, NR);
    scan_bsum_kernel<<<1, 256, 0, stream>>>(bsum_r, nb_r);
    scan_write_kernel<<<nb_r, 256, 0, stream>>>(cnt_r, bsum_r, rs_r, NR, NE);
    hipMemsetAsync(cnt_u, 0, (size_t)NU * 4, stream);
    hipMemsetAsync(cnt_r, 0, (size_t)NR * 4, stream);
    fill_csr_kernel<<<egrid, 256, 0, stream>>>(ru_src, ru_dst, rs_u, cnt_u, csr_u, NE);
    fill_csr_kernel<<<egrid, 256, 0, stream>>>(ur_src, ur_dst, rs_r, cnt_r, csr_r, NE);

    // ---- 3 SAGE layers ----
    const float* cu = x_user;
    const float* cr = x_rest;
    float* nu_[3] = {hu0, hu1, hu0};
    float* nr_[3] = {hr0, hr1, hr0};

    for (int l = 0; l < 3; l++) {
        const float* Wl_r = Wl + (size_t)(l * 2 + 0) * DD * DD;
        const float* Wr_r = Wr + (size_t)(l * 2 + 0) * DD * DD;
        const float* bl_r = bl + (size_t)(l * 2 + 0) * DD;
        const float* Wl_u = Wl + (size_t)(l * 2 + 1) * DD * DD;
        const float* Wr_u = Wr + (size_t)(l * 2 + 1) * DD * DD;
        const float* bl_u = bl + (size_t)(l * 2 + 1) * DD;
        int relu = (l < 2) ? 1 : 0;

        // restaurant side: mean over user rows (ur edges), then linear
        gather_mean_kernel<<<(NR + 3) / 4, 256, 0, stream>>>(cu, csr_r, rs_r, mean, NR);
        sage_linear_kernel<<<(NR + 255) / 256, 256, 0, stream>>>(mean, cr, Wl_r, Wr_r, bl_r, nr_[l], NR, relu);
        // user side: mean over restaurant rows (ru edges), then linear
        gather_mean_kernel<<<(NU + 3) / 4, 256, 0, stream>>>(cr, csr_u, rs_u, mean, NU);
        sage_linear_kernel<<<(NU + 255) / 256, 256, 0, stream>>>(mean, cu, Wl_u, Wr_u, bl_u, nu_[l], NU, relu);

        cu = nu_[l];
        cr = nr_[l];
    }
    // final: cu == hu0, cr == hr0; hu1/hr1 are free -> hold P_u/P_r
    float* P_u = hu1;
    float* P_r = hr1;
    precompute_kernel<<<(NU + 255) / 256, 256, 0, stream>>>(cu, dW1, db1, P_u, NU, 0, 1);
    precompute_kernel<<<(NR + 255) / 256, 256, 0, stream>>>(cr, dW1, db1, P_r, NR, DD, 0);

    decoder_kernel<<<(NQ + 255) / 256, 256, 0, stream>>>(P_u, P_r, el_row, el_col,
                                                         dW2, db2, dW3, db3, out);
}